// Round 4
// baseline (179.741 us; speedup 1.0000x reference)
//
#include <hip/hip_runtime.h>
#include <math.h>

#define B 16
#define D 8
#define FDIM 2
#define N 512
#define E 10          // D + FDIM
#define NP36 36       // pairs a<=d
#define GJW (2*E)     // augmented width for Gauss-Jordan
#define NT 2          // i-halves per (pair,b)
#define TIL 256       // i-tile rows per block
#define KA 12         // augmented K (10 + ca/cb), MFMA K padded to 16
#define NPAIRB (NP36*B*NT)    // 1152 fused pair blocks
#define NMAIN (NPAIRB + B*D)  // + 128 A-path blocks = 1280
#define LOG2E 1.44269504088896340736f

// ---- workspace layout (float offsets) ----
#define OFF_MUD  0      // B*D        = 128
#define OFF_V    128    // B*D*E      = 1280
#define OFF_EDDP 1408   // NP36*B*NT  = 1152
#define OFF_TRP  2560   // D*B*NT     = 256
// total 2816 floats — W/CA/CB now live only in LDS

typedef _Float16 f16x4 __attribute__((ext_vector_type(4)));
typedef float f32x4 __attribute__((ext_vector_type(4)));

// raw hardware exp2 (v_exp_f32); CDNA interlocks handle the TRANS latency
__device__ __forceinline__ float exp2_hw(float x) {
  float r;
  __asm__ __volatile__("v_exp_f32 %0, %1" : "=v"(r) : "v"(x));
  return r;
}

__device__ __forceinline__ void decode_pair(int p36, int* pa, int* pd) {
  int a = 0, rem = p36;
  while (rem >= D - a) { rem -= (D - a); a++; }
  *pa = a; *pd = a + rem;
}

__device__ __forceinline__ float wave_reduce(float v) {
#pragma unroll
  for (int off = 32; off > 0; off >>= 1) v += __shfl_down(v, off);
  return v;
}

// compiler fence for wave-synchronous LDS phases (no runtime cost)
__device__ __forceinline__ void wsync() {
  __asm__ __volatile__("" ::: "memory");
  __builtin_amdgcn_wave_barrier();
  __asm__ __volatile__("" ::: "memory");
}

// Wave-synchronous Gauss-Jordan with partial pivoting on E x GJW system in
// LDS. ONE wave, zero block barriers; reads register-cached before writes
// each phase. On exit: M[r][E+c] = left^{-1} * right.
// Returns log|det(left)| (valid in every lane).
__device__ __forceinline__ float gj_wave(float (*M)[GJW], int lane) {
  float pivs[E];
#pragma unroll
  for (int k = 0; k < E; k++) {
    wsync();
    int pr = k;
    float best = fabsf(M[k][k]);
#pragma unroll
    for (int r = 1; r < E; r++) {
      if (r > k) {
        float v = fabsf(M[r][k]);
        if (v > best) { best = v; pr = r; }
      }
    }
    pivs[k] = M[pr][k];
    wsync();
    float tk = 0.f, pw = 0.f;
    if (lane < GJW) {
      float piv = M[pr][k];
      pw = M[pr][lane] / piv;
      tk = M[k][lane];
    }
    wsync();
    if (lane < GJW) {
      M[pr][lane] = tk;
      M[k][lane]  = pw;
    }
    wsync();
    float cf[4], pv[4], cur[4];
    int rr[4], cc[4];
#pragma unroll
    for (int t = 0; t < 4; t++) {
      int idx = lane + t * 64;
      if (idx < E * GJW) {
        int r = idx / GJW, c = idx - r * GJW;
        rr[t] = r; cc[t] = c;
        cf[t]  = M[r][k];
        pv[t]  = M[k][c];
        cur[t] = M[r][c];
      } else {
        rr[t] = k; cc[t] = 0; cf[t] = 0.f; pv[t] = 0.f; cur[t] = 0.f;
      }
    }
    wsync();
#pragma unroll
    for (int t = 0; t < 4; t++) {
      int idx = lane + t * 64;
      if (idx < E * GJW && rr[t] != k) {
        M[rr[t]][cc[t]] = fmaf(-cf[t], pv[t], cur[t]);
      }
    }
  }
  wsync();
  float ld = 0.f;
#pragma unroll
  for (int k = 0; k < E; k++) ld += logf(fabsf(pivs[k]));
  return ld;
}

// ---------------------------------------------------------------------------
// k_main:
//  blocks [0, NPAIRB): fused (pair,b,i-half) — GJ -> S, W/CA/CB in LDS, then
//    split-f16 MFMA Q contraction -> EDDP (+TRP for diag pairs).
//  blocks [NPAIRB, NMAIN): A-path — mu_delta[b,d], V[b,d,:].
// MFMA layouts (validated in prior rounds):
//   A frag: row=lane&15, k=4*(lane>>4)+t   (T_aug rows, i side)
//   B frag: col=lane&15, k=4*(lane>>4)+t   (nu_aug rows, j side)
//   C/D  : col=lane&15, row=4*(lane>>4)+r
__global__ __launch_bounds__(256) void k_main(
    const float* __restrict__ obs_mean, const float* __restrict__ obs_var,
    const float* __restrict__ action_mean, const float* __restrict__ action_var,
    const float* __restrict__ cross_cov, const float* __restrict__ X,
    const float* __restrict__ ell, const float* __restrict__ alpha_sq,
    const float* __restrict__ beta, const float* __restrict__ invK,
    float* __restrict__ ws) {
  __shared__ __attribute__((aligned(16))) _Float16 snh[N * KA];        // nu_aug hi (j side)
  __shared__ __attribute__((aligned(16))) _Float16 snl[N * KA];        // nu_aug lo
  __shared__ __attribute__((aligned(16))) _Float16 sTh[TIL * KA + 8];  // T_aug hi (+pad)
  __shared__ __attribute__((aligned(16))) _Float16 sTl[TIL * KA + 8];  // T_aug lo
  __shared__ float M[E][GJW];
  __shared__ float sSig[E * E];
  __shared__ float sW[E * E];
  __shared__ float sMu[E], siLa[E], siLd[E];
  __shared__ __attribute__((aligned(16))) float sba[TIL];
  __shared__ float redw[8];
  __shared__ float s_logdet;
  __shared__ float wred[4][11];
  __shared__ float wsh[E];

  int tid = threadIdx.x;
  int bx = blockIdx.x;

  if (bx >= NPAIRB) {
    // ===== A-path: mu_delta[b,d], V[b,d,:] =====
    int bd = bx - NPAIRB;
    int b = bd / D, d = bd % D;
    if (tid < E) {
      sMu[tid] = (tid < D) ? obs_mean[b * D + tid] : action_mean[b * FDIM + tid - D];
    }
    for (int idx = tid; idx < E * E; idx += 256) {
      int e = idx / E, f = idx % E;
      float v;
      if (e < D && f < D)      v = obs_var[(b * D + e) * D + f];
      else if (e < D)          v = cross_cov[(b * D + e) * FDIM + (f - D)];
      else if (f < D)          v = cross_cov[(b * D + f) * FDIM + (e - D)];
      else                     v = action_var[(b * FDIM + (e - D)) * FDIM + (f - D)];
      sSig[idx] = v;
    }
    __syncthreads();
    for (int idx = tid; idx < E * GJW; idx += 256) {
      int r = idx / GJW, c = idx % GJW;
      float v;
      if (c < E) {
        v = sSig[r * E + c];
        if (r == c) { float l = ell[d * E + r]; v += l * l; }
      } else {
        v = (c - E == r) ? 1.0f : 0.0f;
      }
      M[r][c] = v;
    }
    __syncthreads();
    if (tid < 64) {
      float ld = gj_wave(M, tid);            // M[r][E+c] = Ainv
      if (tid == 0) s_logdet = ld;
    }
    __syncthreads();
    float lda = s_logdet;
    float a2 = alpha_sq[d];
    float logdetLam = 0.0f;
#pragma unroll
    for (int e = 0; e < E; e++) { float l = ell[d * E + e]; logdetLam += logf(l * l); }
    float c0 = 0.5f * (logdetLam - lda);
    float acc_mu = 0.0f, acc_w[E];
#pragma unroll
    for (int e = 0; e < E; e++) acc_w[e] = 0.0f;
    for (int n = tid; n < N; n += 256) {
      float x[E];
#pragma unroll
      for (int e = 0; e < E; e++) x[e] = X[n * E + e] - sMu[e];
      float quad = 0.0f;
#pragma unroll
      for (int e = 0; e < E; e++) {
        float te = 0.0f;
#pragma unroll
        for (int f = 0; f < E; f++) te += M[e][E + f] * x[f];
        quad += x[e] * te;
      }
      float qval = a2 * __expf(c0 - 0.5f * quad);
      float bq = beta[d * N + n] * qval;
      acc_mu += bq;
#pragma unroll
      for (int e = 0; e < E; e++) acc_w[e] += bq * x[e];
    }
    int wid = tid >> 6, lane = tid & 63;
    float r = wave_reduce(acc_mu);
    if (lane == 0) wred[wid][0] = r;
#pragma unroll
    for (int e = 0; e < E; e++) {
      r = wave_reduce(acc_w[e]);
      if (lane == 0) wred[wid][e + 1] = r;
    }
    __syncthreads();
    if (tid < 11) {
      float s = wred[0][tid] + wred[1][tid] + wred[2][tid] + wred[3][tid];
      if (tid == 0) ws[OFF_MUD + b * D + d] = s;
      else wsh[tid - 1] = s;
    }
    __syncthreads();
    if (tid == 0) {
      float u[E];
#pragma unroll
      for (int f = 0; f < E; f++) {
        float s = 0.0f;
#pragma unroll
        for (int g = 0; g < E; g++) s += M[f][E + g] * wsh[g];
        u[f] = s;
      }
#pragma unroll
      for (int e = 0; e < E; e++) {
        float s = 0.0f;
#pragma unroll
        for (int f = 0; f < E; f++) s += sSig[e * E + f] * u[f];
        ws[OFF_V + (b * D + d) * E + e] = s;
      }
    }
    return;
  }

  // ===== fused pair path =====
  int tile = bx & (NT - 1);
  int rest = bx >> 1;
  int b = rest & (B - 1);
  int p36 = rest >> 4;
  int a, d;
  decode_pair(p36, &a, &d);
  bool diag = (a == d);
  int i0 = tile * TIL;

  if (tid < E) {
    sMu[tid] = (tid < D) ? obs_mean[b * D + tid] : action_mean[b * FDIM + tid - D];
    float la = ell[a * E + tid]; siLa[tid] = 1.0f / (la * la);
    float ld = ell[d * E + tid]; siLd[tid] = 1.0f / (ld * ld);
  }
  for (int idx = tid; idx < E * E; idx += 256) {
    int e = idx / E, f = idx % E;
    float v;
    if (e < D && f < D)      v = obs_var[(b * D + e) * D + f];
    else if (e < D)          v = cross_cov[(b * D + e) * FDIM + (f - D)];
    else if (f < D)          v = cross_cov[(b * D + f) * FDIM + (e - D)];
    else                     v = action_var[(b * FDIM + (e - D)) * FDIM + (f - D)];
    sSig[idx] = v;
  }
  __syncthreads();
  for (int idx = tid; idx < E * GJW; idx += 256) {
    int r = idx / GJW, c = idx % GJW;
    float v;
    if (c < E) v = sSig[r * E + c] * (siLa[c] + siLd[c]) + ((r == c) ? 1.0f : 0.0f);
    else       v = sSig[r * E + (c - E)];
    M[r][c] = v;
  }
  __syncthreads();
  if (tid < 64) {
    float ld = gj_wave(M, tid);              // M[r][E+f] = S
    if (tid == 0) s_logdet = ld;
  }
  __syncthreads();
  float ldr = s_logdet;
  float lga = logf(alpha_sq[a]);
  float lgd = logf(alpha_sq[d]);
  if (tid < E * E) {
    int e = tid / E, f = tid % E;
    sW[tid] = LOG2E * M[e][E + f] * siLa[e] * siLd[f];
  }

  // j-loop: nu_aug hi/lo rows [x0..x9, 1.0, cb_j] for all 512 j
  for (int jj = tid; jj < N; jj += 256) {
    float x[E], pd_[E];
    float s2b = 0.0f;
#pragma unroll
    for (int e = 0; e < E; e++) {
      float xe = X[jj * E + e] - sMu[e];
      x[e] = xe;
      pd_[e] = xe * siLd[e];
      s2b += xe * pd_[e];
    }
    float db = 0.0f;
#pragma unroll
    for (int e = 0; e < E; e++) {
      float td = 0.0f;
#pragma unroll
      for (int f = 0; f < E; f++) td += M[e][E + f] * pd_[f];
      db += pd_[e] * td;
    }
    float cb = LOG2E * (lgd - 0.5f * s2b + 0.5f * db);
    float v[KA];
#pragma unroll
    for (int e = 0; e < E; e++) v[e] = x[e];
    v[10] = 1.0f;
    v[11] = cb;
#pragma unroll
    for (int k = 0; k < KA; k++) {
      _Float16 h = (_Float16)v[k];
      snh[jj * KA + k] = h;
      snl[jj * KA + k] = (_Float16)(v[k] - (float)h);
    }
  }
  __syncthreads();  // sW/M stable before i-loop reads

  // i-loop: T_aug hi/lo rows [t0..t9, ca_i, 1.0] + sba for this i-half
  {
    int il = tid;  // TIL == 256 == blockDim
    float x[E], pa_[E];
    float s2a = 0.0f;
#pragma unroll
    for (int e = 0; e < E; e++) {
      float xe = X[(i0 + il) * E + e] - sMu[e];
      x[e] = xe;
      pa_[e] = xe * siLa[e];
      s2a += xe * pa_[e];
    }
    float da = 0.0f;
#pragma unroll
    for (int e = 0; e < E; e++) {
      float ta = 0.0f;
#pragma unroll
      for (int f = 0; f < E; f++) ta += M[e][E + f] * pa_[f];
      da += pa_[e] * ta;
    }
    float ca = LOG2E * (lga - 0.5f * s2a + 0.5f * da - 0.5f * ldr);
    float t[KA];
#pragma unroll
    for (int f = 0; f < E; f++) {
      float s = 0.0f;
#pragma unroll
      for (int e = 0; e < E; e++) s = fmaf(x[e], sW[e * E + f], s);
      t[f] = s;
    }
    t[10] = ca;
    t[11] = 1.0f;
#pragma unroll
    for (int k = 0; k < KA; k++) {
      _Float16 h = (_Float16)t[k];
      sTh[il * KA + k] = h;
      sTl[il * KA + k] = (_Float16)(t[k] - (float)h);
    }
    sba[il] = beta[a * N + i0 + il];
  }
  if (tid < 8) { sTh[TIL * KA + tid] = (_Float16)0.f; sTl[TIL * KA + tid] = (_Float16)0.f; }
  __syncthreads();

  // main loop: 4 waves x 8 j-tiles each; 16 i-tiles inner
  int lane = tid & 63;
  int w = tid >> 6;
  int c = lane & 15;
  int kg = lane >> 4;
  bool kval = (kg < 3);
  int koff = kg * 4;
  float accR = 0.f;
  float accT0 = 0.f, accT1 = 0.f, accT2 = 0.f, accT3 = 0.f;
  const float* invKa = invK + (size_t)a * N * N;
  const f32x4 zero4 = {0.f, 0.f, 0.f, 0.f};

  for (int jt8 = 0; jt8 < 8; jt8++) {
    int jt = (w << 3) + jt8;
    int j = (jt << 4) + c;
    f16x4 Bh = {(_Float16)0.f, (_Float16)0.f, (_Float16)0.f, (_Float16)0.f};
    f16x4 Bl = {(_Float16)0.f, (_Float16)0.f, (_Float16)0.f, (_Float16)0.f};
    if (kval) {
      Bh = *(const f16x4*)&snh[j * KA + koff];
      Bl = *(const f16x4*)&snl[j * KA + koff];
    }
    float bd = beta[d * N + j];
    const float* kvrow = invKa + (size_t)j * N + i0 + koff;
#pragma unroll
    for (int it = 0; it < 16; it++) {
      const f16x4 Ah = *(const f16x4*)&sTh[(it * 16 + c) * KA + koff];
      const f16x4 Al = *(const f16x4*)&sTl[(it * 16 + c) * KA + koff];
      f32x4 m = __builtin_amdgcn_mfma_f32_16x16x16f16(Ah, Bh, zero4, 0, 0, 0);
      m = __builtin_amdgcn_mfma_f32_16x16x16f16(Ah, Bl, m, 0, 0, 0);
      m = __builtin_amdgcn_mfma_f32_16x16x16f16(Al, Bh, m, 0, 0, 0);
      float q0 = exp2_hw(m[0]);
      float q1 = exp2_hw(m[1]);
      float q2 = exp2_hw(m[2]);
      float q3 = exp2_hw(m[3]);
      f32x4 ba = *(const f32x4*)&sba[it * 16 + koff];
      float t = ba[0] * q0;
      t = fmaf(ba[1], q1, t);
      t = fmaf(ba[2], q2, t);
      t = fmaf(ba[3], q3, t);
      accR = fmaf(bd, t, accR);
      if (diag) {
        f32x4 r = *(const f32x4*)(kvrow + it * 16);
        accT0 = fmaf(r[0], q0, accT0);
        accT1 = fmaf(r[1], q1, accT1);
        accT2 = fmaf(r[2], q2, accT2);
        accT3 = fmaf(r[3], q3, accT3);
      }
    }
  }

  // reductions (wave shuffle + one LDS step)
  {
    float rr = wave_reduce(accR);
    int wid = tid >> 6, ln = tid & 63;
    if (ln == 0) redw[wid] = rr;
    if (diag) {
      float rt = wave_reduce((accT0 + accT1) + (accT2 + accT3));
      if (ln == 0) redw[4 + wid] = rt;
    }
    __syncthreads();
    if (tid == 0) {
      ws[OFF_EDDP + (p36 * B + b) * NT + tile] = redw[0] + redw[1] + redw[2] + redw[3];
      if (diag)
        ws[OFF_TRP + (a * B + b) * NT + tile] = redw[4] + redw[5] + redw[6] + redw[7];
    }
  }
}

// ---------------------------------------------------------------------------
// k_final: assembly (sums tile partials)
__global__ __launch_bounds__(64) void k_final(
    const float* __restrict__ obs_mean, const float* __restrict__ obs_var,
    const float* __restrict__ alpha_sq, const float* __restrict__ sigma_sq_eps,
    const float* __restrict__ ws, float* __restrict__ out) {
  int b = blockIdx.x;
  int tid = threadIdx.x;
  const float* mud = ws + OFF_MUD + b * D;
  if (tid < D) out[b * D + tid] = obs_mean[b * D + tid] + mud[tid];
  if (tid < D * D) {
    int i = tid / D, j = tid % D;
    int a = i < j ? i : j;
    int dd = i < j ? j : i;
    int p36 = a * D - a * (a - 1) / 2 + (dd - a);
    float edd = 0.0f;
#pragma unroll
    for (int tt = 0; tt < NT; tt++) edd += ws[OFF_EDDP + (p36 * B + b) * NT + tt];
    float sd = edd - mud[i] * mud[j];
    if (i == j) {
      float tr = 0.0f;
#pragma unroll
      for (int tt = 0; tt < NT; tt++) tr += ws[OFF_TRP + (i * B + b) * NT + tt];
      sd += alpha_sq[i] - tr + sigma_sq_eps[i];
    }
    const float* V = ws + OFF_V;
    float cxd = V[(b * D + j) * E + i];   // C_xd[b,i,j] = V[b,j,i]
    float cdx = V[(b * D + i) * E + j];   // C_xd[b,j,i] = V[b,i,j]
    out[B * D + b * D * D + tid] = obs_var[b * D * D + tid] + sd + cxd + cdx;
  }
}

// ---------------------------------------------------------------------------
extern "C" void kernel_launch(void* const* d_in, const int* in_sizes, int n_in,
                              void* d_out, int out_size, void* d_ws, size_t ws_size,
                              hipStream_t stream) {
  const float* obs_mean     = (const float*)d_in[0];
  const float* obs_var      = (const float*)d_in[1];
  const float* action_mean  = (const float*)d_in[2];
  const float* action_var   = (const float*)d_in[3];
  const float* cross_cov    = (const float*)d_in[4];
  const float* X_train      = (const float*)d_in[5];
  const float* ell          = (const float*)d_in[6];
  const float* alpha_sq     = (const float*)d_in[7];
  const float* sigma_sq_eps = (const float*)d_in[8];
  const float* beta         = (const float*)d_in[9];
  const float* inv_K        = (const float*)d_in[10];
  float* out = (float*)d_out;
  float* ws = (float*)d_ws;

  k_main<<<NMAIN, 256, 0, stream>>>(obs_mean, obs_var, action_mean, action_var,
                                    cross_cov, X_train, ell, alpha_sq, beta,
                                    inv_K, ws);
  k_final<<<B, 64, 0, stream>>>(obs_mean, obs_var, alpha_sq, sigma_sq_eps, ws, out);
}